// Round 5
// baseline (202.594 us; speedup 1.0000x reference)
//
#include <hip/hip_runtime.h>

// im2col 3x3 SAME, fp32: x (16,64,128,128) -> out (16,128,128,64,3,3)
// out[b,h,w,c,i,j] = x[b,c,h+i-1,w+j-1] (0 if OOB).
//
// Round-5: "fill-like" store pattern. One WAVE per (b,h) output row:
//   - loads: lane = c; each lane reads 3 rows of its own channel plane,
//     vectorized (x4 + x2 per row per 4-pixel step), L1-resident.
//   - wave-private LDS transpose: 2-slot double buffer, slot = 6-col window
//     [3 rows][6 cols][64 c] (1152 f). NO __syncthreads anywhere: each wave
//     uses only its own LDS region; within-wave ds ordering is lgkmcnt.
//   - stores: lane L holds out floats {q*256 + 4L .. +3} of the 2304-float
//     4-pixel group -> 9 dwordx4 per step, each instr 1 KB fully contiguous;
//     per-wave output stream is 294912 B sequential.  (Round-4 post-mortem:
//     256 B strided granules from 18K waves ~halved effective write BW.)
// 36 LDS gather addresses are per-lane constants (precomputed, unrolled);
// slot parity via 2x unroll so slot offsets are compile-time immediates.

typedef float f4 __attribute__((ext_vector_type(4), aligned(4)));
typedef float f2 __attribute__((ext_vector_type(2), aligned(4)));

#define SLOT 1152   // floats per slot = 3 rows * 6 cols * 64 chans

__global__ __launch_bounds__(256)
void im2col_kernel(const float* __restrict__ x, float* __restrict__ out) {
    __shared__ float lds[4 * 2 * SLOT];   // 4 waves * 2 slots = 36864 B

    const int tid  = threadIdx.x;
    const int wv   = tid >> 6;
    const int lane = tid & 63;
    const int R    = blockIdx.x * 4 + wv;   // row id 0..2047
    const int b    = R >> 7;
    const int h    = R & 127;

    float* sw = lds + wv * (2 * SLOT);

    // ---- per-lane static LDS read offsets (floats within a slot) ----
    // group-local float f = q*256 + 4*lane + e  (4 pixels x 576 els = 2304)
    // f = p*576 + c*9 + i*3 + j ; value lives at slot[i][p+j][c].
    int raddr[9][4];
#pragma unroll
    for (int q = 0; q < 9; ++q)
#pragma unroll
        for (int e = 0; e < 4; ++e) {
            int f   = q * 256 + 4 * lane + e;
            int p   = f / 576;
            int rem = f - 576 * p;
            int cr  = rem / 9;
            int ij  = rem - 9 * cr;
            int i   = ij / 3;
            int j   = ij - 3 * i;
            raddr[q][e] = (i * 6 + p + j) * 64 + cr;
        }

    // ---- this lane's channel plane, 3 row pointers (clamped; zeroed later) ----
    const float* plane = x + ((size_t)b * 64 + lane) * 16384;
    const bool v0 = (h >= 1), v2 = (h <= 126);
    const float* rp0 = plane + (size_t)(v0 ? h - 1 : 0) * 128;
    const float* rp1 = plane + (size_t)h * 128;
    const float* rp2 = plane + (size_t)(v2 ? h + 1 : 0) * 128;

    // ---- prologue: group 0 window (cols -1..4) -> slot 0 ----
    {
        f4 a0 = *(const f4*)(rp0), a1 = *(const f4*)(rp1), a2 = *(const f4*)(rp2);
        float c0 = rp0[4], c1 = rp1[4], c2 = rp2[4];
        if (!v0) { a0 = (f4){0,0,0,0}; c0 = 0.f; }
        if (!v2) { a2 = (f4){0,0,0,0}; c2 = 0.f; }
        float* s = sw + lane;
        s[0]    = 0.f;  s[64]   = a0.x; s[128]  = a0.y; s[192]  = a0.z; s[256]  = a0.w; s[320]  = c0;
        s[384]  = 0.f;  s[448]  = a1.x; s[512]  = a1.y; s[576]  = a1.z; s[640]  = a1.w; s[704]  = c1;
        s[768]  = 0.f;  s[832]  = a2.x; s[896]  = a2.y; s[960]  = a2.z; s[1024] = a2.w; s[1088] = c2;
    }

    float* ob = out + (size_t)R * 73728 + 4 * lane;

#define EMIT(T, SA)                                                          \
    {                                                                        \
        _Pragma("unroll")                                                    \
        for (int q = 0; q < 9; ++q) {                                        \
            f4 o;                                                            \
            o.x = sw[(SA) + raddr[q][0]];                                    \
            o.y = sw[(SA) + raddr[q][1]];                                    \
            o.z = sw[(SA) + raddr[q][2]];                                    \
            o.w = sw[(SA) + raddr[q][3]];                                    \
            *(f4*)(ob + (size_t)(T) * 2304 + q * 256) = o;                   \
        }                                                                    \
    }

#define WRROW(SB, RB, A, Bv)                                                 \
    {                                                                        \
        float* s = sw + (SB) + (RB) + lane;                                  \
        s[0]   = (A).x;  s[64]  = (A).y;  s[128] = (A).z;  s[192] = (A).w;   \
        s[256] = (Bv).x; s[320] = (Bv).y;                                    \
    }

#define STEP(T, SA, SB)                                                      \
    {                                                                        \
        f4 A0 = *(const f4*)(rp0 + 4 * (T) + 3);                             \
        f2 B0 = *(const f2*)(rp0 + 4 * (T) + 7);                             \
        f4 A1 = *(const f4*)(rp1 + 4 * (T) + 3);                             \
        f2 B1 = *(const f2*)(rp1 + 4 * (T) + 7);                             \
        f4 A2 = *(const f4*)(rp2 + 4 * (T) + 3);                             \
        f2 B2 = *(const f2*)(rp2 + 4 * (T) + 7);                             \
        if (!v0) { A0 = (f4){0,0,0,0}; B0 = (f2){0,0}; }                     \
        if (!v2) { A2 = (f4){0,0,0,0}; B2 = (f2){0,0}; }                     \
        EMIT(T, SA);                                                         \
        WRROW(SB, 0,   A0, B0);                                              \
        WRROW(SB, 384, A1, B1);                                              \
        WRROW(SB, 768, A2, B2);                                              \
    }

    // main loop: t = 0..29 (writes groups 1..30, cols <= 124: no clamping)
    for (int tt = 0; tt < 15; ++tt) {
        const int t0 = 2 * tt;
        STEP(t0,     0,    SLOT);   // read slot0, write slot1
        STEP(t0 + 1, SLOT, 0);      // read slot1, write slot0
    }

    // t = 30: read group 30 (slot 0); write group 31 (cols 123..128, 128->0)
    {
        f4 A0 = *(const f4*)(rp0 + 123); float c0 = rp0[127];
        f4 A1 = *(const f4*)(rp1 + 123); float c1 = rp1[127];
        f4 A2 = *(const f4*)(rp2 + 123); float c2 = rp2[127];
        if (!v0) { A0 = (f4){0,0,0,0}; c0 = 0.f; }
        if (!v2) { A2 = (f4){0,0,0,0}; c2 = 0.f; }
        EMIT(30, 0);
        float* s = sw + SLOT + lane;
        s[0]    = A0.x; s[64]   = A0.y; s[128]  = A0.z; s[192]  = A0.w; s[256]  = c0; s[320]  = 0.f;
        s[384]  = A1.x; s[448]  = A1.y; s[512]  = A1.z; s[576]  = A1.w; s[640]  = c1; s[704]  = 0.f;
        s[768]  = A2.x; s[832]  = A2.y; s[896]  = A2.z; s[960]  = A2.w; s[1024] = c2; s[1088] = 0.f;
    }

    // t = 31: read group 31 (slot 1); no writes
    EMIT(31, SLOT);
}

extern "C" void kernel_launch(void* const* d_in, const int* in_sizes, int n_in,
                              void* d_out, int out_size, void* d_ws, size_t ws_size,
                              hipStream_t stream) {
    const float* x = (const float*)d_in[0];
    float* out = (float*)d_out;
    // 2048 rows, 1 wave per row, 4 waves per block -> 512 blocks (2/CU)
    im2col_kernel<<<512, 256, 0, stream>>>(x, out);
}

// Round 6
// 124.579 us; speedup vs baseline: 1.6262x; 1.6262x over previous
//
#include <hip/hip_runtime.h>

// im2col 3x3 SAME, fp32: x (16,64,128,128) -> out (16,128,128,64,3,3)
// out[b,h,w,c,i,j] = x[b,c,h+i-1,w+j-1] (0 if OOB).
//
// Round-6: round-4 structure (no LDS, no barrier, lane = el = c*9+i*3+j,
// thread sweeps w with float4 input loads; per-wave 256 B contiguous dword
// stores) + NONTEMPORAL stores.
// Rationale: r1-r5 (four disjoint structures) all plateau at ~3.3 TB/s
// effective while plain fills on the same buffer do 6.75 TB/s. Best-fit
// model: store-miss write-allocate in L2/MALL adds a hidden ~604 MB fetch
// (dur ~= (604W + 604RFO + 64R)/6.6 TB/s ~= 195 us observed). nt stores
// take the streaming/no-allocate path, eliminating the RFO.

typedef float f4 __attribute__((ext_vector_type(4), aligned(4)));

__global__ __launch_bounds__(576)
void im2col_kernel(const float* __restrict__ x, float* __restrict__ out) {
    const int el = threadIdx.x;          // 0..575
    const int bid = blockIdx.x;
    const int h = bid & 127;             // H = 128
    const int b = bid >> 7;

    // el -> (c, i, j), once
    const int c  = el / 9;
    const int ij = el - c * 9;
    const int i  = ij / 3;
    const int j  = ij - i * 3;

    const int row = h + i - 1;
    const bool rv = (unsigned)row < 128u;
    const float* rp = x + ((size_t)b * 64 + c) * 16384 + (rv ? row : 0) * 128;
    const int j1 = j - 1;

    float* ob = out + (size_t)bid * (128 * 576) + el;

    // ---- w = 0 (col = j1 may be -1) ----
    {
        int col = j1;
        float v = rp[col < 0 ? 0 : col];
        __builtin_nontemporal_store((rv && col >= 0) ? v : 0.0f, ob);
    }

    // ---- w = 1..124: 31 x { one float4 load, four nt dword stores } ----
#pragma unroll 4
    for (int it = 0; it < 31; ++it) {
        int w = 1 + (it << 2);
        f4 v = *(const f4*)(rp + w + j1);   // 4B-aligned dwordx4
        if (!rv) { v.x = 0.0f; v.y = 0.0f; v.z = 0.0f; v.w = 0.0f; }
        float* o = ob + (size_t)w * 576;
        __builtin_nontemporal_store(v.x, o);
        __builtin_nontemporal_store(v.y, o + 576);
        __builtin_nontemporal_store(v.z, o + 2 * 576);
        __builtin_nontemporal_store(v.w, o + 3 * 576);
    }

    // ---- w = 125..127 (col may reach 128) ----
#pragma unroll
    for (int w = 125; w < 128; ++w) {
        int col = w + j1;
        float v = rp[col > 127 ? 127 : col];
        __builtin_nontemporal_store((rv && col <= 127) ? v : 0.0f,
                                    ob + (size_t)w * 576);
    }
}

extern "C" void kernel_launch(void* const* d_in, const int* in_sizes, int n_in,
                              void* d_out, int out_size, void* d_ws, size_t ws_size,
                              hipStream_t stream) {
    const float* x = (const float*)d_in[0];
    float* out = (float*)d_out;
    // blocks = 16 b * 128 h = 2048; each block emits one full (b,h) out-row
    im2col_kernel<<<2048, 576, 0, stream>>>(x, out);
}

// Round 7
// 119.922 us; speedup vs baseline: 1.6894x; 1.0388x over previous
//
#include <hip/hip_runtime.h>

// im2col 3x3 SAME, fp32: x (16,64,128,128) -> out (16,128,128,64,3,3)
// out[b,h,w,c,i,j] = x[b,c,h+i-1,w+j-1] (0 if OOB).
//
// Round-7 = round-6 (no LDS, no barrier, lane = el = c*9+i*3+j, float4
// input loads, NONTEMPORAL dword stores -> no write-allocate RFO) + T1
// XCD-chunked block swizzle.
// r6 post-mortem: nt stores confirmed the RFO theory (195 -> 124.6 us).
// Residual vs ~99 us floor modeled as input over-fetch (~3x64 MB): each x
// row feeds h-1/h/h+1 blocks, which round-robin dispatch scatters across
// XCD L2s. Swizzle (bijective, 2048 %% 8 == 0): XCD k := rows
// [k*256,(k+1)*256) = 2 whole batch planes in increasing h -> sliding
// 3-row window stays L2-resident, each input row fetched ~once.

typedef float f4 __attribute__((ext_vector_type(4), aligned(4)));

__global__ __launch_bounds__(576)
void im2col_kernel(const float* __restrict__ x, float* __restrict__ out) {
    const int el = threadIdx.x;          // 0..575

    // XCD-aware swizzle: HW round-robins blockIdx across 8 XCDs.
    // R = (bid%8)*256 + bid/8 gives XCD k the contiguous row range.
    const int bid = blockIdx.x;
    const int R   = ((bid & 7) << 8) + (bid >> 3);   // bijective on [0,2048)
    const int h = R & 127;               // H = 128
    const int b = R >> 7;

    // el -> (c, i, j), once
    const int c  = el / 9;
    const int ij = el - c * 9;
    const int i  = ij / 3;
    const int j  = ij - i * 3;

    const int row = h + i - 1;
    const bool rv = (unsigned)row < 128u;
    const float* rp = x + ((size_t)b * 64 + c) * 16384 + (rv ? row : 0) * 128;
    const int j1 = j - 1;

    float* ob = out + (size_t)R * (128 * 576) + el;

    // ---- w = 0 (col = j1 may be -1) ----
    {
        int col = j1;
        float v = rp[col < 0 ? 0 : col];
        __builtin_nontemporal_store((rv && col >= 0) ? v : 0.0f, ob);
    }

    // ---- w = 1..124: 31 x { one float4 load, four nt dword stores } ----
#pragma unroll 4
    for (int it = 0; it < 31; ++it) {
        int w = 1 + (it << 2);
        f4 v = *(const f4*)(rp + w + j1);   // 4B-aligned dwordx4
        if (!rv) { v.x = 0.0f; v.y = 0.0f; v.z = 0.0f; v.w = 0.0f; }
        float* o = ob + (size_t)w * 576;
        __builtin_nontemporal_store(v.x, o);
        __builtin_nontemporal_store(v.y, o + 576);
        __builtin_nontemporal_store(v.z, o + 2 * 576);
        __builtin_nontemporal_store(v.w, o + 3 * 576);
    }

    // ---- w = 125..127 (col may reach 128) ----
#pragma unroll
    for (int w = 125; w < 128; ++w) {
        int col = w + j1;
        float v = rp[col > 127 ? 127 : col];
        __builtin_nontemporal_store((rv && col <= 127) ? v : 0.0f,
                                    ob + (size_t)w * 576);
    }
}

extern "C" void kernel_launch(void* const* d_in, const int* in_sizes, int n_in,
                              void* d_out, int out_size, void* d_ws, size_t ws_size,
                              hipStream_t stream) {
    const float* x = (const float*)d_in[0];
    float* out = (float*)d_out;
    // blocks = 16 b * 128 h = 2048; each block emits one full (b,h) out-row
    im2col_kernel<<<2048, 576, 0, stream>>>(x, out);
}